// Round 2
// baseline (30.617 us; speedup 1.0000x reference)
//
#include <hip/hip_runtime.h>
#include <math.h>

// BlockwiseQuantizationOptim: 1024x1024 f32, 64 blocks of 128x128, L=256, T=100.
// Closed-form softmax over uniform levels: e_l = r^{|p-l|}, r = exp(-100/255).
//   S  = r^f*A[k] + r^(1-f)*A[254-k]
//   W  = r^f*(k*A[k]-B[k]) + r^(1-f)*((k+1)*A[254-k]+B[254-k])
// A[k]=sum r^m, B[k]=sum m r^m (LDS tables). bin_mass = two impulse deposits
// per element + geometric scans per column (register-local + shfl carry scan).
//
// dep LDS layout permuted to kill scan-phase bank conflicts:
//   idx(c,l) = (l&15)*272 + c*17 + (l>>4)   (~2-3-way max aliasing)

#define NT 512
#define LVL 256
#define DEPIDX(c, l) ((((l) & 15) * 272) + ((c) * 17) + ((l) >> 4))

__global__ __launch_bounds__(NT)
void bq_main(const float* __restrict__ Wt,
             const float* __restrict__ wmin_in,
             const float* __restrict__ wmax_in,
             float* __restrict__ dq_out,
             float* __restrict__ ent_out)
{
    __shared__ float tabA[LVL], tabB[LVL];
    __shared__ float dep[2][4352];   // [dir][permuted (i,col,ch)]
    __shared__ float wred[8];

    const int tid = threadIdx.x;
    const int wg  = blockIdx.x;
    const int n = wg >> 3, slab = wg & 7;   // block 0..63, 16-col slab 0..7

    const float LN2 = 0.69314718055994531f;
    const float L2R = -(100.0f / 255.0f) * 1.4426950408889634f;  // log2(r)
    const float r = __builtin_amdgcn_exp2f(L2R);
    const float inv1mr = 1.0f / (1.0f - r);

    if (tid < LVL) {
        const float rk1 = __builtin_amdgcn_exp2f(L2R * (float)(tid + 1)); // r^{k+1}
        tabA[tid] = (1.0f - rk1) * inv1mr;
        tabB[tid] = (r - (float)(tid + 1) * rk1 + (float)tid * rk1 * r)
                    * (inv1mr * inv1mr);
    }
    for (int q = tid; q < 2 * 4352; q += NT) (&dep[0][0])[q] = 0.0f;

    const float bmn = wmin_in[n], bmx = wmax_in[n];
    const float wmn = fminf(bmn, bmx - 1e-6f);
    const float wmx = fmaxf(bmx, wmn + 1e-6f);
    const float scale = wmx - wmn;
    const float invsc = 1.0f / (scale + 1e-6f);

    __syncthreads();

    // ---- phase 1: closed-form softmax + dequant + 2 deposits per element
    {
        const int row = tid >> 2;              // 0..127
        const int c0  = (tid & 3) * 4;         // 0,4,8,12
        const int R = (n >> 3) * 128 + row;
        const int C = (n & 7) * 128 + slab * 16 + c0;
        const float4 x4 = *reinterpret_cast<const float4*>(Wt + (size_t)R * 1024 + C);
        float xs[4] = {x4.x, x4.y, x4.z, x4.w};
        float dq[4];
        #pragma unroll
        for (int u = 0; u < 4; ++u) {
            const float p = (xs[u] - wmn) * invsc * 255.0f;   // in [0,255)
            int k = (int)p; k = (k > 254) ? 254 : k;
            const float f   = p - (float)k;
            const float rf  = __builtin_amdgcn_exp2f(L2R * f);
            const float r1f = __builtin_amdgcn_exp2f(L2R * (1.0f - f));
            const int ku = 254 - k;
            const float Ak = tabA[k],  Bk = tabB[k];
            const float Au = tabA[ku], Bu = tabB[ku];
            const float S  = rf * Ak + r1f * Au;
            const float Wn = rf * ((float)k * Ak - Bk)
                           + r1f * ((float)(k + 1) * Au + Bu);
            const float invS = __builtin_amdgcn_rcpf(S);
            dq[u] = Wn * invS * (1.0f / 255.0f) * scale + wmn;
            const int c = c0 + u;
            atomicAdd(&dep[0][DEPIDX(c, k)],     rf  * invS);  // down-chain seed
            atomicAdd(&dep[1][DEPIDX(c, k + 1)], r1f * invS);  // up-chain seed
        }
        float4 o4; o4.x = dq[0]; o4.y = dq[1]; o4.z = dq[2]; o4.w = dq[3];
        *reinterpret_cast<float4*>(dq_out + (size_t)R * 1024 + C) = o4;
    }
    __syncthreads();

    // ---- phase 2: geometric scans; thread = (dir, col, ch), 16 levels/chunk
    {
        const int ch  = tid & 15;
        const int col = (tid >> 4) & 15;
        const int dir = tid >> 8;              // 0: down (hi->lo), 1: up
        float* arr = &dep[dir][0];
        const int base = col * 17 + ch;
        float lv[16];
        float v = 0.0f;
        if (dir == 0) {
            #pragma unroll
            for (int i = 15; i >= 0; --i) { v = v * r + arr[i * 272 + base]; lv[i] = v; }
        } else {
            #pragma unroll
            for (int i = 0; i < 16; ++i) { v = v * r + arr[i * 272 + base]; lv[i] = v; }
        }
        // cross-chunk carry: weighted Hillis-Steele scan over 16 chunks (in-wave)
        const float r16 = __builtin_amdgcn_exp2f(L2R * 16.0f);
        float u = v;
        float rp = r16;
        #pragma unroll
        for (int s = 1; s <= 8; s <<= 1) {
            const float o = (dir == 0) ? __shfl_down(u, s, 16) : __shfl_up(u, s, 16);
            const bool ok = (dir == 0) ? (ch + s < 16) : (ch >= s);
            u += ok ? rp * o : 0.0f;
            rp *= rp;
        }
        float cv;
        if (dir == 0) cv = (ch < 15) ? __shfl_down(u, 1, 16) : 0.0f;
        else          cv = (ch > 0)  ? __shfl_up(u, 1, 16)  : 0.0f;
        float m = cv * r;
        if (dir == 0) {
            #pragma unroll
            for (int i = 15; i >= 0; --i) { arr[i * 272 + base] = lv[i] + m; m *= r; }
        } else {
            #pragma unroll
            for (int i = 0; i < 16; ++i) { arr[i * 272 + base] = lv[i] + m; m *= r; }
        }
    }
    __syncthreads();

    // ---- phase 3: entropy over this slab's 16x256 bins (fast log)
    float hsum = 0.0f;
    #pragma unroll
    for (int t = 0; t < 8; ++t) {
        const int q = tid + t * NT;
        const int c = q & 15, l = q >> 4;
        const int idx = DEPIDX(c, l);
        const float b  = dep[0][idx] + dep[1][idx];
        const float ph = b * (1.0f / 16384.0f);
        hsum -= ph * (__builtin_amdgcn_logf(ph + 1e-6f) * LN2);
    }
    #pragma unroll
    for (int off = 32; off > 0; off >>= 1) hsum += __shfl_down(hsum, off);
    if ((tid & 63) == 0) wred[tid >> 6] = hsum;
    __syncthreads();
    if (tid == 0) {
        float tot = 0.0f;
        #pragma unroll
        for (int w = 0; w < 8; ++w) tot += wred[w];
        atomicAdd(ent_out, tot);
    }
}

extern "C" void kernel_launch(void* const* d_in, const int* in_sizes, int n_in,
                              void* d_out, int out_size, void* d_ws, size_t ws_size,
                              hipStream_t stream)
{
    const float* Wt  = (const float*)d_in[0];
    const float* wmn = (const float*)d_in[1];
    const float* wmx = (const float*)d_in[2];
    float* out = (float*)d_out;   // [1048576 dequant] + [1 entropy]

    hipMemsetAsync(out + 1048576, 0, sizeof(float), stream);
    bq_main<<<512, NT, 0, stream>>>(Wt, wmn, wmx, out, out + 1048576);
}

// Round 3
// 12.468 us; speedup vs baseline: 2.4556x; 2.4556x over previous
//
#include <hip/hip_runtime.h>
#include <math.h>

// BlockwiseQuantizationOptim: 1024x1024 f32, 64 blocks of 128x128, L=256, T=100.
// Closed-form softmax over uniform levels: e_l = r^{|p-l|}, r = exp(-100/255).
//   S  = rf*A[k] + r1f*A[j],          j = 254-k
//   W  = rf*(k*A[k]-B[k]) + r1f*((255-j)*A[j]+B[j])
// A[k]=sum_{m<=k} r^m, B[k]=sum m r^m. Folded tables:
//   tabK[k] = (A[k], k*A[k]-B[k])     (down side, index k)
//   tabJ[j] = (A[j], (255-j)*A[j]+B[j]) (up side, index j)
// bin_mass: two impulse deposits per element (FIXED-POINT u32 -> native
// ds_add_u32, no CAS loop) + geometric scans per column (register-local +
// in-wave shfl carry scan).
//
// dep LDS layout permuted for scan-phase bank spread:
//   idx(c,l) = (l&15)*272 + c*17 + (l>>4)

#define NT 512
#define LVL 256
#define FXS 8388608.0f            // 2^23
#define INV_FXS (1.0f / 8388608.0f)
#define DEPIDX(c, l) ((((l) & 15) * 272) + ((c) * 17) + ((l) >> 4))

__global__ __launch_bounds__(NT)
void bq_main(const float* __restrict__ Wt,
             const float* __restrict__ wmin_in,
             const float* __restrict__ wmax_in,
             float* __restrict__ dq_out,
             float* __restrict__ partials)
{
    __shared__ float2 tabK[LVL];      // (A[k], k*A[k]-B[k])
    __shared__ float2 tabJ[LVL];      // (A[j], (255-j)*A[j]+B[j])
    __shared__ unsigned dep[2][4352]; // [dir][permuted (i,col,ch)] fixed-point
    __shared__ float wred[8];

    const int tid = threadIdx.x;
    const int wg  = blockIdx.x;
    const int n = wg >> 3, slab = wg & 7;   // block 0..63, 16-col slab 0..7

    const float LN2 = 0.69314718055994531f;
    const float L2R = -(100.0f / 255.0f) * 1.4426950408889634f;  // log2(r)
    const float r = __builtin_amdgcn_exp2f(L2R);
    const float inv1mr = 1.0f / (1.0f - r);

    if (tid < LVL) {
        const int k = tid;
        const float rk1 = __builtin_amdgcn_exp2f(L2R * (float)(k + 1)); // r^{k+1}
        const float A = (1.0f - rk1) * inv1mr;
        const float B = (r - (float)(k + 1) * rk1 + (float)k * rk1 * r)
                        * (inv1mr * inv1mr);
        tabK[k] = make_float2(A, (float)k * A - B);
        tabJ[k] = make_float2(A, (float)(255 - k) * A + B);
    }
    for (int q = tid; q < 2 * 4352; q += NT) (&dep[0][0])[q] = 0u;

    const float bmn = wmin_in[n], bmx = wmax_in[n];
    const float wmn = fminf(bmn, bmx - 1e-6f);
    const float wmx = fmaxf(bmx, wmn + 1e-6f);
    const float scale = wmx - wmn;
    const float invsc = 255.0f / (scale + 1e-6f);
    const float sc255 = scale * (1.0f / 255.0f);

    __syncthreads();

    // ---- phase 1: closed-form softmax + dequant + 2 fixed-point deposits/elem
    {
        const int row = tid >> 2;              // 0..127
        const int c0  = (tid & 3) * 4;         // 0,4,8,12
        const int R = (n >> 3) * 128 + row;
        const int C = (n & 7) * 128 + slab * 16 + c0;
        const float4 x4 = *reinterpret_cast<const float4*>(Wt + (size_t)R * 1024 + C);
        float xs[4] = {x4.x, x4.y, x4.z, x4.w};
        float dq[4];
        #pragma unroll
        for (int u = 0; u < 4; ++u) {
            const float p = (xs[u] - wmn) * invsc;   // in [0,255)
            int k = (int)p; k = (k > 254) ? 254 : k;
            const float f   = p - (float)k;
            const float rf  = __builtin_amdgcn_exp2f(L2R * f);
            const float r1f = __builtin_amdgcn_exp2f(L2R * (1.0f - f));
            const float2 K = tabK[k];
            const float2 J = tabJ[254 - k];
            const float S  = rf * K.x + r1f * J.x;
            const float Wn = rf * K.y + r1f * J.y;
            const float invS = __builtin_amdgcn_rcpf(S);
            dq[u] = Wn * invS * sc255 + wmn;
            const int c = c0 + u;
            atomicAdd(&dep[0][DEPIDX(c, k)],     (unsigned)(rf  * invS * FXS + 0.5f));
            atomicAdd(&dep[1][DEPIDX(c, k + 1)], (unsigned)(r1f * invS * FXS + 0.5f));
        }
        float4 o4; o4.x = dq[0]; o4.y = dq[1]; o4.z = dq[2]; o4.w = dq[3];
        *reinterpret_cast<float4*>(dq_out + (size_t)R * 1024 + C) = o4;
    }
    __syncthreads();

    // ---- phase 2: geometric scans; thread = (dir, col, ch), 16 levels/chunk
    // reads u32 fixed-point, writes back float (disjoint per-thread ownership)
    {
        const int ch  = tid & 15;
        const int col = (tid >> 4) & 15;
        const int dir = tid >> 8;              // 0: down (hi->lo), 1: up
        unsigned* au = &dep[dir][0];
        float*    af = reinterpret_cast<float*>(au);
        const int base = col * 17 + ch;
        float lv[16];
        float v = 0.0f;
        if (dir == 0) {
            #pragma unroll
            for (int i = 15; i >= 0; --i) {
                v = v * r + (float)au[i * 272 + base] * INV_FXS;
                lv[i] = v;
            }
        } else {
            #pragma unroll
            for (int i = 0; i < 16; ++i) {
                v = v * r + (float)au[i * 272 + base] * INV_FXS;
                lv[i] = v;
            }
        }
        // cross-chunk carry: weighted Hillis-Steele over 16 chunks, in-wave
        const float r16 = __builtin_amdgcn_exp2f(L2R * 16.0f);
        float u = v;
        float rp = r16;
        #pragma unroll
        for (int s = 1; s <= 8; s <<= 1) {
            const float o = (dir == 0) ? __shfl_down(u, s, 16) : __shfl_up(u, s, 16);
            const bool ok = (dir == 0) ? (ch + s < 16) : (ch >= s);
            u += ok ? rp * o : 0.0f;
            rp *= rp;
        }
        float cv;
        if (dir == 0) cv = (ch < 15) ? __shfl_down(u, 1, 16) : 0.0f;
        else          cv = (ch > 0)  ? __shfl_up(u, 1, 16)  : 0.0f;
        float m = cv * r;
        if (dir == 0) {
            #pragma unroll
            for (int i = 15; i >= 0; --i) { af[i * 272 + base] = lv[i] + m; m *= r; }
        } else {
            #pragma unroll
            for (int i = 0; i < 16; ++i) { af[i * 272 + base] = lv[i] + m; m *= r; }
        }
    }
    __syncthreads();

    // ---- phase 3: entropy over this slab's 16x256 bins
    const float* d0 = reinterpret_cast<const float*>(&dep[0][0]);
    const float* d1 = reinterpret_cast<const float*>(&dep[1][0]);
    float hsum = 0.0f;
    #pragma unroll
    for (int t = 0; t < 8; ++t) {
        const int q = tid + t * NT;
        const int c = q & 15, l = q >> 4;
        const int idx = DEPIDX(c, l);
        const float b  = d0[idx] + d1[idx];
        const float ph = b * (1.0f / 16384.0f);
        hsum -= ph * (__builtin_amdgcn_logf(ph + 1e-6f) * LN2);
    }
    #pragma unroll
    for (int off = 32; off > 0; off >>= 1) hsum += __shfl_down(hsum, off);
    if ((tid & 63) == 0) wred[tid >> 6] = hsum;
    __syncthreads();
    if (tid == 0) {
        float tot = 0.0f;
        #pragma unroll
        for (int w = 0; w < 8; ++w) tot += wred[w];
        partials[wg] = tot;
    }
}

__global__ __launch_bounds__(256)
void bq_finish(const float* __restrict__ partials, float* __restrict__ ent_out)
{
    const int tid = threadIdx.x;
    float v = partials[tid] + partials[tid + 256];
    #pragma unroll
    for (int off = 32; off > 0; off >>= 1) v += __shfl_down(v, off);
    __shared__ float buf[4];
    if ((tid & 63) == 0) buf[tid >> 6] = v;
    __syncthreads();
    if (tid == 0) ent_out[0] = buf[0] + buf[1] + buf[2] + buf[3];
}

extern "C" void kernel_launch(void* const* d_in, const int* in_sizes, int n_in,
                              void* d_out, int out_size, void* d_ws, size_t ws_size,
                              hipStream_t stream)
{
    const float* Wt  = (const float*)d_in[0];
    const float* wmn = (const float*)d_in[1];
    const float* wmx = (const float*)d_in[2];
    float* out = (float*)d_out;      // [1048576 dequant] + [1 entropy]
    float* partials = (float*)d_ws;  // 512 floats

    bq_main<<<512, NT, 0, stream>>>(Wt, wmn, wmx, out, partials);
    bq_finish<<<1, 256, 0, stream>>>(partials, out + 1048576);
}